// Round 7
// baseline (78.916 us; speedup 1.0000x reference)
//
#include <hip/hip_runtime.h>
#include <hip/hip_bf16.h>

// Problem constants (reference: N=2048, D=512, T=0.1, sigma=1, 4 classes)
#define D 512
#define INV_T 10.0f
#define INF_VAL 1e8f

#define BM 128
#define BK 64
#define KSTEPS (D / BK)              // 8
#define NTB 32                       // 4096/128 tiles per dim
#define NBLK (NTB * (NTB + 1) / 2)   // 528 upper-triangle tiles
#define TTBLK 64                     // tt-role blocks appended to k_gemm grid
#define NSLOT 192                    // 64 forward + 128 transpose partial slots

typedef short bf16x8 __attribute__((ext_vector_type(8)));
typedef float f32x4 __attribute__((ext_vector_type(4)));

typedef __attribute__((address_space(3))) unsigned int lds_uint;
typedef __attribute__((address_space(1))) unsigned int gbl_uint;

__device__ __forceinline__ void async_copy16(const ushort* gsrc, ushort* ldst) {
  // 64 lanes x 16B -> 1 KB; LDS dest = wave-uniform base + lane*16 (linear)
  __builtin_amdgcn_global_load_lds((const gbl_uint*)gsrc, (lds_uint*)ldst, 16, 0, 0);
}

__device__ inline float wave_reduce_sum(float v) {
#pragma unroll
  for (int off = 32; off > 0; off >>= 1) v += __shfl_xor(v, off);
  return v;
}

__device__ __forceinline__ ushort f2bf(float x) {
  __hip_bfloat16 h = __float2bfloat16(x);
  return *reinterpret_cast<ushort*>(&h);
}

// -------------------------------------------------------------------------
// Fused prep:
//   blocks [0,1024):      normalize+cast zb (wave-per-row, 4 rows/block)
//   blocks [1024,3072):   sinv[j] = 1/(2*shalf[j]-1)
//   blocks [3072,4608):   zero-fill s_ws/c_ws (NSLOT partial-slot buffers)
__global__ __launch_bounds__(256) void k_prep(const float* __restrict__ zi,
                                              const float* __restrict__ zj,
                                              ushort* __restrict__ zb,
                                              const int* __restrict__ labels,
                                              const float* __restrict__ zpos,
                                              float* __restrict__ sinv,
                                              float* __restrict__ zfill, int N) {
  int b = blockIdx.x;
  if (b < 1024) {
    // --- normcast: one row per wave ---
    int wv = threadIdx.x >> 6, lane = threadIdx.x & 63;
    int row = b * 4 + wv;
    const float* src = (row < N) ? (zi + (size_t)row * D) : (zj + (size_t)(row - N) * D);
    const float4* s4 = reinterpret_cast<const float4*>(src);
    float4 v0 = s4[lane];
    float4 v1 = s4[lane + 64];
    float ss = 0.f;
    ss = fmaf(v0.x, v0.x, ss); ss = fmaf(v0.y, v0.y, ss);
    ss = fmaf(v0.z, v0.z, ss); ss = fmaf(v0.w, v0.w, ss);
    ss = fmaf(v1.x, v1.x, ss); ss = fmaf(v1.y, v1.y, ss);
    ss = fmaf(v1.z, v1.z, ss); ss = fmaf(v1.w, v1.w, ss);
    ss = wave_reduce_sum(ss);
    float sc = 1.0f / fmaxf(sqrtf(ss), 1e-12f);
    ushort4 o0 = {f2bf(v0.x * sc), f2bf(v0.y * sc), f2bf(v0.z * sc), f2bf(v0.w * sc)};
    ushort4 o1 = {f2bf(v1.x * sc), f2bf(v1.y * sc), f2bf(v1.z * sc), f2bf(v1.w * sc)};
    ushort4* dst = reinterpret_cast<ushort4*>(zb + (size_t)row * D);
    dst[lane] = o0;
    dst[lane + 64] = o1;
  } else if (b < 3072) {
    // --- colsum: one j per block ---
    __shared__ float scratch[4];
    int j = b - 1024;
    int lj = labels[j];
    float pj = zpos[j];
    float s = 0.f;
    for (int i = threadIdx.x; i < N; i += 256) {
      if (labels[i] == lj) {
        float d = zpos[i] - pj;
        s += __expf(-0.5f * d * d);
      }
    }
    s = wave_reduce_sum(s);
    int lane = threadIdx.x & 63, wv = threadIdx.x >> 6;
    if (lane == 0) scratch[wv] = s;
    __syncthreads();
    if (threadIdx.x == 0) {
      float t = scratch[0] + scratch[1] + scratch[2] + scratch[3];
      sinv[j] = 1.0f / (2.0f * t - 1.0f);
    }
  } else {
    // --- zero-fill the 2*NSLOT*2N floats of s_ws|c_ws (contiguous) ---
    size_t idx = (size_t)(b - 3072) * 256 + threadIdx.x;
    float4 z = {0.f, 0.f, 0.f, 0.f};
    reinterpret_cast<float4*>(zfill)[idx] = z;
  }
}

// -------------------------------------------------------------------------
// Symmetric GEMM + dual epilogue + folded tt computation.
// Blocks [0,528): upper-triangle 128x128 tiles, 8 waves (512 thr), each wave
//   a 32x64 sub-tile. Double-buffered LDS with COUNTED vmcnt (T4): loads
//   stay in flight a full K-step; raw s_barrier pairs, no vmcnt(0) drain in
//   the main loop. Diag blocks stage B redundantly for a uniform load count.
// Blocks [528,592): tt[i] = sum_j same(i,j)*rbf(i,j)*sinv[j], 32 rows/block.
// Partial slots: forward slot = ct*2+wc (row sums over that 64-col range),
// transpose slot = 64 + rt*4 + wr (col sums over that wave's 32 rows).
// Every (slot,row) cell written at most once; unwritten cells are zero
// (k_prep zero-fill), so k_combine can sum all slots.
__global__ __launch_bounds__(512, 4) void k_gemm(
    const ushort* __restrict__ zb, const int* __restrict__ labels,
    const float* __restrict__ zpos, const float* __restrict__ sinv,
    float* __restrict__ tt,
    float* __restrict__ s_ws, float* __restrict__ c_ws, int N) {
  const int tid = threadIdx.x;
  const int bid = blockIdx.x;
  const int twoN = 2 * N;

  if (bid >= NBLK) {
    // ---- tt role ----
    int base = (bid - NBLK) * 32;
    int i = base + (tid >> 4);
    int part = tid & 15;
    int li = labels[i];
    float pi = zpos[i];
    int seg = N >> 4;              // 128
    float s = 0.f;
    for (int j = part * seg; j < (part + 1) * seg; ++j) {
      if (labels[j] == li) {
        float d = zpos[j] - pi;
        s += __expf(-0.5f * d * d) * sinv[j];
      }
    }
    s += __shfl_xor(s, 1); s += __shfl_xor(s, 2);
    s += __shfl_xor(s, 4); s += __shfl_xor(s, 8);
    if (part == 0) tt[i] = s;
    return;
  }

  __shared__ __align__(16) ushort sT[2][2][BM * BK];   // [buf][A/B], 64 KB

  const int lane = tid & 63;
  const int wv = tid >> 6;        // 0..7
  const int wr = wv >> 1;         // 0..3 (32-row strip)
  const int wc = wv & 1;          // 0..1 (64-col half)
  const int colq = lane & 15;
  const int laneg = lane >> 4;

  // XCD swizzle (528 % 8 == 0 -> bijective), triangle unrank
  int L = (bid & 7) * (NBLK / 8) + (bid >> 3);
  int u = L, rt = 0;
  while (u >= NTB - rt) { u -= NTB - rt; ++rt; }
  const int ct = rt + u;                 // rt <= ct
  const bool diag = (rt == ct);
  const int rowBase = rt * BM;
  const int colBase = ct * BM;

  // staging: 1 inst = 8 rows x 128B; LDS linear, source pre-swizzled so the
  // read-side XOR (slot ^ row&7) finds the data (rule #21 both-sides pair)
  const int srow = lane >> 3;
  const int sslot = (lane & 7) ^ srow;

  f32x4 acc[2][4] = {};

  // each wave stages A rows [wv*16,+16) and B rows [wv*16,+16): 4 insts/step
#define STAGE(buf, kt)                                                        \
  {                                                                           \
    _Pragma("unroll")                                                         \
    for (int q = 0; q < 2; ++q) {                                             \
      int rloc = wv * 16 + q * 8;                                             \
      async_copy16(zb + (size_t)(rowBase + rloc + srow) * D + (kt) * BK +     \
                       sslot * 8,                                             \
                   (ushort*)sT[buf][0] + rloc * BK);                          \
      async_copy16(zb + (size_t)(colBase + rloc + srow) * D + (kt) * BK +     \
                       sslot * 8,                                             \
                   (ushort*)sT[buf][1] + rloc * BK);                          \
    }                                                                         \
  }

  STAGE(0, 0);
  int cur = 0;
#pragma unroll
  for (int kt = 0; kt < KSTEPS; ++kt) {
    if (kt + 1 < KSTEPS) {
      STAGE(cur ^ 1, kt + 1);
      // wait for buf[cur]'s 4 loads (issued last iter, ~full K-step ago);
      // the 4 just-issued stay in flight across the barrier (T4)
      asm volatile("s_waitcnt vmcnt(4)" ::: "memory");
    } else {
      asm volatile("s_waitcnt vmcnt(0)" ::: "memory");
    }
    __builtin_amdgcn_s_barrier();          // all waves' buf[cur] resident
    __builtin_amdgcn_sched_barrier(0);

    const char* Ab = reinterpret_cast<const char*>(sT[cur][0]);
    const char* Bb = reinterpret_cast<const char*>(sT[cur][1]);
#pragma unroll
    for (int kk = 0; kk < 2; ++kk) {
      bf16x8 a[2], b[4];
      const int slot = kk * 4 + laneg;
#pragma unroll
      for (int rf = 0; rf < 2; ++rf) {
        int r = wr * 32 + rf * 16 + colq;
        a[rf] = *reinterpret_cast<const bf16x8*>(Ab + r * 128 + (slot ^ (r & 7)) * 16);
      }
#pragma unroll
      for (int cf = 0; cf < 4; ++cf) {
        int c = wc * 64 + cf * 16 + colq;
        b[cf] = *reinterpret_cast<const bf16x8*>(Bb + c * 128 + (slot ^ (c & 7)) * 16);
      }
#pragma unroll
      for (int rf = 0; rf < 2; ++rf)
#pragma unroll
        for (int cf = 0; cf < 4; ++cf)
          acc[rf][cf] = __builtin_amdgcn_mfma_f32_16x16x32_bf16(a[rf], b[cf], acc[rf][cf], 0, 0, 0);
    }
    __builtin_amdgcn_sched_barrier(0);
    __builtin_amdgcn_s_barrier();          // all waves done reading buf[cur]
    cur ^= 1;
  }
#undef STAGE

  // ---- dual epilogue ----
  // C layout: col = lane&15, row = (lane>>4)*4 + reg  [m89 verified]
  const int wRowBase = rowBase + wr * 32;
  const int wColBase = colBase + wc * 64;
  const int rmodBase = (wRowBase >= N) ? wRowBase - N : wRowBase;
  const int cmodBase = (wColBase >= N) ? wColBase - N : wColBase;

  float rpos[8], rsinv[8];
  unsigned rlab = 0;
#pragma unroll
  for (int rf = 0; rf < 2; ++rf)
#pragma unroll
    for (int rg = 0; rg < 4; ++rg) {
      int idx = rf * 4 + rg;
      int r = rmodBase + rf * 16 + laneg * 4 + rg;
      rpos[idx] = zpos[r];
      rsinv[idx] = sinv[r];
      rlab |= ((unsigned)labels[r] & 3u) << (idx * 2);
    }

  float s_p[8], c_p[8], sc_p[4], cc_p[4];
#pragma unroll
  for (int i = 0; i < 8; ++i) { s_p[i] = 0.f; c_p[i] = 0.f; }

#pragma unroll
  for (int cf = 0; cf < 4; ++cf) {
    int jc = cmodBase + cf * 16 + colq;
    int lc = labels[jc];
    float pc = zpos[jc];
    float si = sinv[jc];
    int col = wColBase + cf * 16 + colq;
    float scf = 0.f, ccf = 0.f;
#pragma unroll
    for (int rf = 0; rf < 2; ++rf)
#pragma unroll
      for (int rg = 0; rg < 4; ++rg) {
        int idx = rf * 4 + rg;
        int row = wRowBase + rf * 16 + laneg * 4 + rg;
        float sim = acc[rf][cf][rg] * INV_T;
        bool dg = (row == col);
        if (dg) sim = -INF_VAL;
        float e = __expf(sim - 10.f);          // exp(-1e8)==0: diag drops out
        s_p[idx] += e;                          // forward row-sum
        scf += e;                               // transpose col-sum
        int lr = (int)((rlab >> (idx * 2)) & 3u);
        if (lr == lc && !dg) {
          float d = rpos[idx] - pc;
          float w = __expf(-0.5f * d * d);
          c_p[idx] = fmaf(w * si, sim, c_p[idx]);        // fw[r,c] = w*sinv[c]
          ccf = fmaf(w * rsinv[idx], sim, ccf);          // fw[c,r] = w*sinv[r]
        }
      }
    sc_p[cf] = scf;
    cc_p[cf] = ccf;
  }

  // forward: reduce each row over the 16 lanes sharing it
#pragma unroll
  for (int idx = 0; idx < 8; ++idx) {
#pragma unroll
    for (int off = 1; off < 16; off <<= 1) {
      s_p[idx] += __shfl_xor(s_p[idx], off);
      c_p[idx] += __shfl_xor(c_p[idx], off);
    }
  }
  if (colq == 0) {
    int slot = ct * 2 + wc;
#pragma unroll
    for (int rf = 0; rf < 2; ++rf)
#pragma unroll
      for (int rg = 0; rg < 4; ++rg) {
        int idx = rf * 4 + rg;
        int row = wRowBase + rf * 16 + laneg * 4 + rg;
        s_ws[(size_t)slot * twoN + row] = s_p[idx];
        c_ws[(size_t)slot * twoN + row] = c_p[idx];
      }
  }

  // transpose: reduce each column over laneg groups (lanes colq,+16,+32,+48)
  if (!diag) {
#pragma unroll
    for (int cf = 0; cf < 4; ++cf) {
      sc_p[cf] += __shfl_xor(sc_p[cf], 16);
      sc_p[cf] += __shfl_xor(sc_p[cf], 32);
      cc_p[cf] += __shfl_xor(cc_p[cf], 16);
      cc_p[cf] += __shfl_xor(cc_p[cf], 32);
    }
    if (laneg == 0) {
      int slot = 64 + rt * 4 + wr;
#pragma unroll
      for (int cf = 0; cf < 4; ++cf) {
        int rowt = wColBase + cf * 16 + colq;
        s_ws[(size_t)slot * twoN + rowt] = sc_p[cf];
        c_ws[(size_t)slot * twoN + rowt] = cc_p[cf];
      }
    }
  }
}

// -------------------------------------------------------------------------
// Per-row combine + block partial sum. 64 blocks x 64 rows.
// partial[a] = cross_a - wsum_a * (10 + log(sum_slots s_ws))
__global__ __launch_bounds__(256) void k_combine(const float* __restrict__ s_ws,
                                                 const float* __restrict__ c_ws,
                                                 const float* __restrict__ sinv,
                                                 const float* __restrict__ tt,
                                                 float* __restrict__ bsum, int N) {
  __shared__ float sS[4][64], sC[4][64];
  int b = blockIdx.x, t = threadIdx.x;
  int r = t & 63, g = t >> 6;
  int twoN = 2 * N;
  int a = b * 64 + r;
  float s = 0.f, c = 0.f;
  for (int k = 0; k < NSLOT / 4; ++k) {
    int sl = g * (NSLOT / 4) + k;
    s += s_ws[(size_t)sl * twoN + a];
    c += c_ws[(size_t)sl * twoN + a];
  }
  sS[g][r] = s;
  sC[g][r] = c;
  __syncthreads();
  if (t < 64) {
    float st = sS[0][t] + sS[1][t] + sS[2][t] + sS[3][t];
    float ct = sC[0][t] + sC[1][t] + sC[2][t] + sC[3][t];
    int aa = b * 64 + t;
    int ir = (aa >= N) ? aa - N : aa;
    float lse = 10.f + logf(st);
    float wsum = 2.f * tt[ir] - sinv[ir];
    float p = ct - wsum * lse;
    p = wave_reduce_sum(p);
    if (t == 0) bsum[b] = p;
  }
}

// loss = (-1/N) * sum_b bsum[b]
__global__ __launch_bounds__(64) void k_final(const float* __restrict__ bsum,
                                              float* __restrict__ out, int N) {
  float s = bsum[threadIdx.x];
  s = wave_reduce_sum(s);
  if (threadIdx.x == 0) out[0] = (-1.0f / (float)N) * s;
}

extern "C" void kernel_launch(void* const* d_in, const int* in_sizes, int n_in,
                              void* d_out, int out_size, void* d_ws, size_t ws_size,
                              hipStream_t stream) {
  (void)n_in; (void)out_size; (void)ws_size;
  const float* zi = (const float*)d_in[0];
  const float* zj = (const float*)d_in[1];
  const int* labels = (const int*)d_in[2];
  const float* zpos = (const float*)d_in[3];
  float* out = (float*)d_out;

  const int N = in_sizes[2];       // 2048
  const int twoN = 2 * N;

  // workspace: zb bf16[2N*D] | sinv[N] | tt[N] | s_ws[NSLOT*2N] | c_ws[...] | bsum[64]
  char* wsb = (char*)d_ws;
  ushort* zb = (ushort*)wsb;                              // 4 MB
  float* sinv = (float*)(wsb + (size_t)twoN * D * 2);
  float* tt = sinv + N;
  float* s_ws = tt + N;                                   // 3 MB
  float* c_ws = s_ws + (size_t)NSLOT * twoN;              // 3 MB (contiguous after s_ws)
  float* bsum = c_ws + (size_t)NSLOT * twoN;

  // zero-fill range: s_ws..c_ws end = 2*NSLOT*twoN floats = 393216 float4
  k_prep<<<1024 + 2048 + 1536, 256, 0, stream>>>(zi, zj, zb, labels, zpos, sinv, s_ws, N);
  k_gemm<<<NBLK + TTBLK, 512, 0, stream>>>(zb, labels, zpos, sinv, tt, s_ws, c_ws, N);
  k_combine<<<twoN / 64, 256, 0, stream>>>(s_ws, c_ws, sinv, tt, bsum, N);
  k_final<<<1, 64, 0, stream>>>(bsum, out, N);
}

// Round 8
// 65.101 us; speedup vs baseline: 1.2122x; 1.2122x over previous
//
#include <hip/hip_runtime.h>
#include <hip/hip_bf16.h>

// Problem constants (reference: N=2048, D=512, T=0.1, sigma=1, 4 classes)
#define D 512
#define INV_T 10.0f
#define INF_VAL 1e8f

#define TILE 64
#define BK 64
#define KSTEPS (D / BK)               // 8
#define NTB 64                        // 4096/64 tiles per dim
#define NBLK (NTB * (NTB + 1) / 2)    // 2080 upper-triangle tiles (2080%8==0)
#define TTBLK 128                     // tt-role blocks appended to k_gemm grid
#define NSLOT 128                     // 32-col chunks (shared fwd/transpose buffer)

typedef short bf16x8 __attribute__((ext_vector_type(8)));
typedef float f32x4 __attribute__((ext_vector_type(4)));

typedef __attribute__((address_space(3))) unsigned int lds_uint;
typedef __attribute__((address_space(1))) unsigned int gbl_uint;

__device__ __forceinline__ void async_copy16(const ushort* gsrc, ushort* ldst) {
  // 64 lanes x 16B -> 1 KB; LDS dest = wave-uniform base + lane*16 (linear)
  __builtin_amdgcn_global_load_lds((const gbl_uint*)gsrc, (lds_uint*)ldst, 16, 0, 0);
}

__device__ inline float wave_reduce_sum(float v) {
#pragma unroll
  for (int off = 32; off > 0; off >>= 1) v += __shfl_xor(v, off);
  return v;
}

__device__ __forceinline__ ushort f2bf(float x) {
  __hip_bfloat16 h = __float2bfloat16(x);
  return *reinterpret_cast<ushort*>(&h);
}

// -------------------------------------------------------------------------
// Fused prep:
//   blocks [0,1024):    normalize+cast zb (wave-per-row, 4 rows/block)
//   blocks [1024,3072): sinv[j] = 1/(2*shalf[j]-1)
__global__ __launch_bounds__(256) void k_prep(const float* __restrict__ zi,
                                              const float* __restrict__ zj,
                                              ushort* __restrict__ zb,
                                              const int* __restrict__ labels,
                                              const float* __restrict__ zpos,
                                              float* __restrict__ sinv, int N) {
  int b = blockIdx.x;
  if (b < 1024) {
    // --- normcast: one row per wave ---
    int wv = threadIdx.x >> 6, lane = threadIdx.x & 63;
    int row = b * 4 + wv;
    const float* src = (row < N) ? (zi + (size_t)row * D) : (zj + (size_t)(row - N) * D);
    const float4* s4 = reinterpret_cast<const float4*>(src);
    float4 v0 = s4[lane];
    float4 v1 = s4[lane + 64];
    float ss = 0.f;
    ss = fmaf(v0.x, v0.x, ss); ss = fmaf(v0.y, v0.y, ss);
    ss = fmaf(v0.z, v0.z, ss); ss = fmaf(v0.w, v0.w, ss);
    ss = fmaf(v1.x, v1.x, ss); ss = fmaf(v1.y, v1.y, ss);
    ss = fmaf(v1.z, v1.z, ss); ss = fmaf(v1.w, v1.w, ss);
    ss = wave_reduce_sum(ss);
    float sc = 1.0f / fmaxf(sqrtf(ss), 1e-12f);
    ushort4 o0 = {f2bf(v0.x * sc), f2bf(v0.y * sc), f2bf(v0.z * sc), f2bf(v0.w * sc)};
    ushort4 o1 = {f2bf(v1.x * sc), f2bf(v1.y * sc), f2bf(v1.z * sc), f2bf(v1.w * sc)};
    ushort4* dst = reinterpret_cast<ushort4*>(zb + (size_t)row * D);
    dst[lane] = o0;
    dst[lane + 64] = o1;
  } else {
    // --- colsum: one j per block ---
    __shared__ float scratch[4];
    int j = b - 1024;
    int lj = labels[j];
    float pj = zpos[j];
    float s = 0.f;
    for (int i = threadIdx.x; i < N; i += 256) {
      if (labels[i] == lj) {
        float d = zpos[i] - pj;
        s += __expf(-0.5f * d * d);
      }
    }
    s = wave_reduce_sum(s);
    int lane = threadIdx.x & 63, wv = threadIdx.x >> 6;
    if (lane == 0) scratch[wv] = s;
    __syncthreads();
    if (threadIdx.x == 0) {
      float t = scratch[0] + scratch[1] + scratch[2] + scratch[3];
      sinv[j] = 1.0f / (2.0f * t - 1.0f);
    }
  }
}

// -------------------------------------------------------------------------
// Symmetric GEMM + dual epilogue + folded tt.
// Blocks [0,2080): upper-triangle 64x64 tiles. 4 waves (2x2), each a 32x32
//   sub-tile. Single-buffered 16 KB LDS, stage -> sync -> compute -> sync
//   (round-5 proven core); latency hidden by ~4 blocks/CU TLP.
// Blocks [2080,2208): tt[i] = sum_j same(i,j)*rbf(i,j)*sinv[j], 16 rows/blk.
// Partial slots (32-col chunks, m in [0,128)): forward writes (m=ct*2+wc,
// rows in rt-tile) covering p<=q; transpose writes (m=rt*2+wr, rows in
// ct-tile) covering p>q (diag skipped). Disjoint + complete -> one shared
// buffer, every cell written exactly once, no zero-fill.
__global__ __launch_bounds__(256, 4) void k_gemm(
    const ushort* __restrict__ zb, const int* __restrict__ labels,
    const float* __restrict__ zpos, const float* __restrict__ sinv,
    float* __restrict__ tt,
    float* __restrict__ s_ws, float* __restrict__ c_ws, int N) {
  const int tid = threadIdx.x;
  const int bid = blockIdx.x;
  const int twoN = 2 * N;

  if (bid >= NBLK) {
    // ---- tt role: 16 rows/block, 16 threads/row ----
    int i = (bid - NBLK) * 16 + (tid >> 4);
    int part = tid & 15;
    int li = labels[i];
    float pi = zpos[i];
    int seg = N >> 4;              // 128
    float s = 0.f;
    for (int j = part * seg; j < (part + 1) * seg; ++j) {
      if (labels[j] == li) {
        float d = zpos[j] - pi;
        s += __expf(-0.5f * d * d) * sinv[j];
      }
    }
    s += __shfl_xor(s, 1); s += __shfl_xor(s, 2);
    s += __shfl_xor(s, 4); s += __shfl_xor(s, 8);
    if (part == 0) tt[i] = s;
    return;
  }

  __shared__ __align__(16) ushort As[TILE * BK];   // 8 KB
  __shared__ __align__(16) ushort Bs[TILE * BK];   // 8 KB

  const int lane = tid & 63;
  const int wv = tid >> 6;        // 0..3
  const int wr = wv >> 1;         // row half
  const int wc = wv & 1;          // col half
  const int colq = lane & 15;
  const int laneg = lane >> 4;

  // XCD swizzle (2080 % 8 == 0 -> bijective), then triangle unrank
  int L = (bid & 7) * (NBLK / 8) + (bid >> 3);
  int u = L, rt = 0;
  while (u >= NTB - rt) { u -= NTB - rt; ++rt; }
  const int ct = rt + u;                 // rt <= ct
  const bool diag = (rt == ct);
  const int rowBase = rt * TILE;
  const int colBase = ct * TILE;

  // staging: 1 inst = 8 rows x 128B; LDS linear, source pre-swizzled so the
  // read-side XOR (slot ^ row&7) finds the data (rule #21 both-sides pair)
  const int srow = lane >> 3;
  const int sslot = (lane & 7) ^ srow;

  f32x4 acc[2][2] = {};

  for (int kt = 0; kt < KSTEPS; ++kt) {
    // ---- stage: wave wv stages rows [wv*16, wv*16+16) of A (and B) ----
#pragma unroll
    for (int q = 0; q < 2; ++q) {
      int rloc = wv * 16 + q * 8;
      async_copy16(zb + (size_t)(rowBase + rloc + srow) * D + kt * BK + sslot * 8,
                   (ushort*)As + rloc * BK);
      if (!diag)
        async_copy16(zb + (size_t)(colBase + rloc + srow) * D + kt * BK + sslot * 8,
                     (ushort*)Bs + rloc * BK);
    }
    __syncthreads();   // drains vmcnt: tile resident

    const char* Ab = reinterpret_cast<const char*>(As);
    const char* Bb = diag ? Ab : reinterpret_cast<const char*>(Bs);
#pragma unroll
    for (int kk = 0; kk < 2; ++kk) {
      bf16x8 a[2], b[2];
      const int slot = kk * 4 + laneg;
#pragma unroll
      for (int rf = 0; rf < 2; ++rf) {
        int r = wr * 32 + rf * 16 + colq;
        a[rf] = *reinterpret_cast<const bf16x8*>(Ab + r * 128 + (slot ^ (r & 7)) * 16);
      }
#pragma unroll
      for (int cf = 0; cf < 2; ++cf) {
        int c = wc * 32 + cf * 16 + colq;
        b[cf] = *reinterpret_cast<const bf16x8*>(Bb + c * 128 + (slot ^ (c & 7)) * 16);
      }
#pragma unroll
      for (int rf = 0; rf < 2; ++rf)
#pragma unroll
        for (int cf = 0; cf < 2; ++cf)
          acc[rf][cf] = __builtin_amdgcn_mfma_f32_16x16x32_bf16(a[rf], b[cf], acc[rf][cf], 0, 0, 0);
    }
    if (kt + 1 < KSTEPS) __syncthreads();   // LDS free for next K-tile
  }

  // ---- dual epilogue ----
  // C layout: col = lane&15, row = (lane>>4)*4 + reg  [m89 verified]
  const int wRowBase = rowBase + wr * 32;
  const int wColBase = colBase + wc * 32;
  const int rmodBase = (wRowBase >= N) ? wRowBase - N : wRowBase;
  const int cmodBase = (wColBase >= N) ? wColBase - N : wColBase;

  float rpos[8], rsinv[8];
  unsigned rlab = 0;
#pragma unroll
  for (int rf = 0; rf < 2; ++rf)
#pragma unroll
    for (int rg = 0; rg < 4; ++rg) {
      int idx = rf * 4 + rg;
      int r = rmodBase + rf * 16 + laneg * 4 + rg;
      rpos[idx] = zpos[r];
      rsinv[idx] = sinv[r];
      rlab |= ((unsigned)labels[r] & 3u) << (idx * 2);
    }

  float s_p[8], c_p[8], sc_p[2], cc_p[2];
#pragma unroll
  for (int i = 0; i < 8; ++i) { s_p[i] = 0.f; c_p[i] = 0.f; }

#pragma unroll
  for (int cf = 0; cf < 2; ++cf) {
    int jc = cmodBase + cf * 16 + colq;
    int lc = labels[jc];
    float pc = zpos[jc];
    float si = sinv[jc];
    int col = wColBase + cf * 16 + colq;
    float scf = 0.f, ccf = 0.f;
#pragma unroll
    for (int rf = 0; rf < 2; ++rf)
#pragma unroll
      for (int rg = 0; rg < 4; ++rg) {
        int idx = rf * 4 + rg;
        int row = wRowBase + rf * 16 + laneg * 4 + rg;
        float sim = acc[rf][cf][rg] * INV_T;
        bool dg = (row == col);
        if (dg) sim = -INF_VAL;
        float e = __expf(sim - 10.f);          // exp(-1e8)==0: diag drops out
        s_p[idx] += e;                          // forward row-sum
        scf += e;                               // transpose col-sum
        int lr = (int)((rlab >> (idx * 2)) & 3u);
        if (lr == lc && !dg) {
          float d = rpos[idx] - pc;
          float w = __expf(-0.5f * d * d);
          c_p[idx] = fmaf(w * si, sim, c_p[idx]);        // fw[r,c] = w*sinv[c]
          ccf = fmaf(w * rsinv[idx], sim, ccf);          // fw[c,r] = w*sinv[r]
        }
      }
    sc_p[cf] = scf;
    cc_p[cf] = ccf;
  }

  // forward: reduce each row over the 16 lanes sharing it
#pragma unroll
  for (int idx = 0; idx < 8; ++idx) {
#pragma unroll
    for (int off = 1; off < 16; off <<= 1) {
      s_p[idx] += __shfl_xor(s_p[idx], off);
      c_p[idx] += __shfl_xor(c_p[idx], off);
    }
  }
  if (colq == 0) {
    int m = ct * 2 + wc;
#pragma unroll
    for (int rf = 0; rf < 2; ++rf)
#pragma unroll
      for (int rg = 0; rg < 4; ++rg) {
        int idx = rf * 4 + rg;
        int row = wRowBase + rf * 16 + laneg * 4 + rg;
        s_ws[(size_t)m * twoN + row] = s_p[idx];
        c_ws[(size_t)m * twoN + row] = c_p[idx];
      }
  }

  // transpose: reduce each column over laneg groups (lanes colq,+16,+32,+48)
  if (!diag) {
#pragma unroll
    for (int cf = 0; cf < 2; ++cf) {
      sc_p[cf] += __shfl_xor(sc_p[cf], 16);
      sc_p[cf] += __shfl_xor(sc_p[cf], 32);
      cc_p[cf] += __shfl_xor(cc_p[cf], 16);
      cc_p[cf] += __shfl_xor(cc_p[cf], 32);
    }
    if (laneg == 0) {
      int m = rt * 2 + wr;
#pragma unroll
      for (int cf = 0; cf < 2; ++cf) {
        int rowt = wColBase + cf * 16 + colq;
        s_ws[(size_t)m * twoN + rowt] = sc_p[cf];
        c_ws[(size_t)m * twoN + rowt] = cc_p[cf];
      }
    }
  }
}

// -------------------------------------------------------------------------
// Per-row combine + block partial sum. 64 blocks x 64 rows.
// partial[a] = cross_a - wsum_a * (10 + log(sum_m s_ws[m][a]))
__global__ __launch_bounds__(256) void k_combine(const float* __restrict__ s_ws,
                                                 const float* __restrict__ c_ws,
                                                 const float* __restrict__ sinv,
                                                 const float* __restrict__ tt,
                                                 float* __restrict__ bsum, int N) {
  __shared__ float sS[4][64], sC[4][64];
  int b = blockIdx.x, t = threadIdx.x;
  int r = t & 63, g = t >> 6;
  int twoN = 2 * N;
  int a = b * 64 + r;
  float s = 0.f, c = 0.f;
  for (int k = 0; k < NSLOT / 4; ++k) {
    int m = g * (NSLOT / 4) + k;
    s += s_ws[(size_t)m * twoN + a];
    c += c_ws[(size_t)m * twoN + a];
  }
  sS[g][r] = s;
  sC[g][r] = c;
  __syncthreads();
  if (t < 64) {
    float st = sS[0][t] + sS[1][t] + sS[2][t] + sS[3][t];
    float ct = sC[0][t] + sC[1][t] + sC[2][t] + sC[3][t];
    int aa = b * 64 + t;
    int ir = (aa >= N) ? aa - N : aa;
    float lse = 10.f + logf(st);
    float wsum = 2.f * tt[ir] - sinv[ir];
    float p = ct - wsum * lse;
    p = wave_reduce_sum(p);
    if (t == 0) bsum[b] = p;
  }
}

// loss = (-1/N) * sum_b bsum[b]
__global__ __launch_bounds__(64) void k_final(const float* __restrict__ bsum,
                                              float* __restrict__ out, int N) {
  float s = bsum[threadIdx.x];
  s = wave_reduce_sum(s);
  if (threadIdx.x == 0) out[0] = (-1.0f / (float)N) * s;
}

extern "C" void kernel_launch(void* const* d_in, const int* in_sizes, int n_in,
                              void* d_out, int out_size, void* d_ws, size_t ws_size,
                              hipStream_t stream) {
  (void)n_in; (void)out_size; (void)ws_size;
  const float* zi = (const float*)d_in[0];
  const float* zj = (const float*)d_in[1];
  const int* labels = (const int*)d_in[2];
  const float* zpos = (const float*)d_in[3];
  float* out = (float*)d_out;

  const int N = in_sizes[2];       // 2048
  const int twoN = 2 * N;

  // workspace: zb bf16[2N*D] | sinv[N] | tt[N] | s_ws[128*2N] | c_ws[128*2N] | bsum[64]
  char* wsb = (char*)d_ws;
  ushort* zb = (ushort*)wsb;                              // 4 MB
  float* sinv = (float*)(wsb + (size_t)twoN * D * 2);
  float* tt = sinv + N;
  float* s_ws = tt + N;                                   // 2 MB
  float* c_ws = s_ws + (size_t)NSLOT * twoN;              // 2 MB
  float* bsum = c_ws + (size_t)NSLOT * twoN;

  k_prep<<<1024 + 2048, 256, 0, stream>>>(zi, zj, zb, labels, zpos, sinv, N);
  k_gemm<<<NBLK + TTBLK, 256, 0, stream>>>(zb, labels, zpos, sinv, tt, s_ws, c_ws, N);
  k_combine<<<twoN / 64, 256, 0, stream>>>(s_ws, c_ws, sinv, tt, bsum, N);
  k_final<<<1, 64, 0, stream>>>(bsum, out, N);
}

// Round 9
// 60.141 us; speedup vs baseline: 1.3122x; 1.0825x over previous
//
#include <hip/hip_runtime.h>
#include <hip/hip_bf16.h>

// Problem constants (reference: N=2048, D=512, T=0.1, sigma=1, 4 classes)
#define D 512
#define INV_T 10.0f
#define INF_VAL 1e8f

#define BM 128
#define BK 64
#define KSTEPS (D / BK)              // 8
#define NTB 32                       // 4096/128 tiles per dim
#define NBLK (NTB * (NTB + 1) / 2)   // 528 upper-triangle tiles (528%8==0)
#define TTBLK 128                    // tt-role blocks appended to k_gemm grid
#define NCHUNK 64                    // 64-col chunks; fwd/transpose share disjointly

typedef short bf16x8 __attribute__((ext_vector_type(8)));
typedef float f32x4 __attribute__((ext_vector_type(4)));

typedef __attribute__((address_space(3))) unsigned int lds_uint;
typedef __attribute__((address_space(1))) unsigned int gbl_uint;

__device__ __forceinline__ void async_copy16(const ushort* gsrc, ushort* ldst) {
  // 64 lanes x 16B -> 1 KB; LDS dest = wave-uniform base + lane*16 (linear)
  __builtin_amdgcn_global_load_lds((const gbl_uint*)gsrc, (lds_uint*)ldst, 16, 0, 0);
}

__device__ inline float wave_reduce_sum(float v) {
#pragma unroll
  for (int off = 32; off > 0; off >>= 1) v += __shfl_xor(v, off);
  return v;
}

__device__ __forceinline__ ushort f2bf(float x) {
  __hip_bfloat16 h = __float2bfloat16(x);
  return *reinterpret_cast<ushort*>(&h);
}

// -------------------------------------------------------------------------
// Fused prep (proven R8):
//   blocks [0,1024):    normalize+cast zb (wave-per-row, 4 rows/block)
//   blocks [1024,3072): sinv[j] = 1/(2*shalf[j]-1)
__global__ __launch_bounds__(256) void k_prep(const float* __restrict__ zi,
                                              const float* __restrict__ zj,
                                              ushort* __restrict__ zb,
                                              const int* __restrict__ labels,
                                              const float* __restrict__ zpos,
                                              float* __restrict__ sinv, int N) {
  int b = blockIdx.x;
  if (b < 1024) {
    int wv = threadIdx.x >> 6, lane = threadIdx.x & 63;
    int row = b * 4 + wv;
    const float* src = (row < N) ? (zi + (size_t)row * D) : (zj + (size_t)(row - N) * D);
    const float4* s4 = reinterpret_cast<const float4*>(src);
    float4 v0 = s4[lane];
    float4 v1 = s4[lane + 64];
    float ss = 0.f;
    ss = fmaf(v0.x, v0.x, ss); ss = fmaf(v0.y, v0.y, ss);
    ss = fmaf(v0.z, v0.z, ss); ss = fmaf(v0.w, v0.w, ss);
    ss = fmaf(v1.x, v1.x, ss); ss = fmaf(v1.y, v1.y, ss);
    ss = fmaf(v1.z, v1.z, ss); ss = fmaf(v1.w, v1.w, ss);
    ss = wave_reduce_sum(ss);
    float sc = 1.0f / fmaxf(sqrtf(ss), 1e-12f);
    ushort4 o0 = {f2bf(v0.x * sc), f2bf(v0.y * sc), f2bf(v0.z * sc), f2bf(v0.w * sc)};
    ushort4 o1 = {f2bf(v1.x * sc), f2bf(v1.y * sc), f2bf(v1.z * sc), f2bf(v1.w * sc)};
    ushort4* dst = reinterpret_cast<ushort4*>(zb + (size_t)row * D);
    dst[lane] = o0;
    dst[lane + 64] = o1;
  } else {
    __shared__ float scratch[4];
    int j = b - 1024;
    int lj = labels[j];
    float pj = zpos[j];
    float s = 0.f;
    for (int i = threadIdx.x; i < N; i += 256) {
      if (labels[i] == lj) {
        float d = zpos[i] - pj;
        s += __expf(-0.5f * d * d);
      }
    }
    s = wave_reduce_sum(s);
    int lane = threadIdx.x & 63, wv = threadIdx.x >> 6;
    if (lane == 0) scratch[wv] = s;
    __syncthreads();
    if (threadIdx.x == 0) {
      float t = scratch[0] + scratch[1] + scratch[2] + scratch[3];
      sinv[j] = 1.0f / (2.0f * t - 1.0f);
    }
  }
}

// -------------------------------------------------------------------------
// Symmetric GEMM + dual epilogue (proven R5 core) + folded tt (proven R8).
// Blocks [0,528): upper-triangle 128x128 tiles, 4 waves (2x2), each 64x64.
//   Double-buffered 64 KB LDS, prefetch-next-before-compute, one
//   __syncthreads per K-step. Diag tiles stage A only (B == A).
// Blocks [528,656): tt[i] = sum_j same(i,j)*rbf(i,j)*sinv[j], 16 rows/blk.
// Partial slots (64-col chunks, m in [0,64)): forward m=ct*2+wc, rows in
// rt-tile (p<=q); transpose m=rt*2+wr, rows in ct-tile (p>q; diag skipped).
// Disjoint + complete -> every cell written exactly once, no zero-fill.
__global__ __launch_bounds__(256, 2) void k_gemm(
    const ushort* __restrict__ zb, const int* __restrict__ labels,
    const float* __restrict__ zpos, const float* __restrict__ sinv,
    float* __restrict__ tt,
    float* __restrict__ s_ws, float* __restrict__ c_ws, int N) {
  const int tid = threadIdx.x;
  const int bid = blockIdx.x;
  const int twoN = 2 * N;

  if (bid >= NBLK) {
    // ---- tt role: 16 rows/block, 16 threads/row ----
    int i = (bid - NBLK) * 16 + (tid >> 4);
    int part = tid & 15;
    int li = labels[i];
    float pi = zpos[i];
    int seg = N >> 4;              // 128
    float s = 0.f;
    for (int j = part * seg; j < (part + 1) * seg; ++j) {
      if (labels[j] == li) {
        float d = zpos[j] - pi;
        s += __expf(-0.5f * d * d) * sinv[j];
      }
    }
    s += __shfl_xor(s, 1); s += __shfl_xor(s, 2);
    s += __shfl_xor(s, 4); s += __shfl_xor(s, 8);
    if (part == 0) tt[i] = s;
    return;
  }

  __shared__ __align__(16) ushort sT[2][2][BM * BK];   // [buf][A/B], 64 KB

  const int lane = tid & 63;
  const int wv = tid >> 6;        // 0..3
  const int wr = wv >> 1;         // row half
  const int wc = wv & 1;          // col half
  const int colq = lane & 15;
  const int laneg = lane >> 4;

  // XCD swizzle (528 % 8 == 0 -> bijective), then triangle unrank
  int L = (bid & 7) * (NBLK / 8) + (bid >> 3);
  int u = L, rt = 0;
  while (u >= NTB - rt) { u -= NTB - rt; ++rt; }
  const int ct = rt + u;                 // rt <= ct
  const bool diag = (rt == ct);
  const int rowBase = rt * BM;
  const int colBase = ct * BM;

  // staging: 1 inst = 8 rows x 128B; LDS linear, source pre-swizzled so the
  // read-side XOR (slot ^ row&7) finds the data (rule #21 both-sides pair)
  const int srow = lane >> 3;
  const int sslot = (lane & 7) ^ srow;

  f32x4 acc[4][4] = {};

  // ---- prologue: stage K-tile 0 into buffer 0 ----
#pragma unroll
  for (int q = 0; q < 4; ++q) {
    int rloc = wv * 32 + q * 8;
    async_copy16(zb + (size_t)(rowBase + rloc + srow) * D + 0 * BK + sslot * 8,
                 (ushort*)sT[0][0] + rloc * BK);
    if (!diag)
      async_copy16(zb + (size_t)(colBase + rloc + srow) * D + 0 * BK + sslot * 8,
                   (ushort*)sT[0][1] + rloc * BK);
  }
  __syncthreads();

  int cur = 0;
#pragma unroll
  for (int kt = 0; kt < KSTEPS; ++kt) {
    // ---- prefetch next K-tile into the other buffer (overlaps compute) ----
    if (kt + 1 < KSTEPS) {
#pragma unroll
      for (int q = 0; q < 4; ++q) {
        int rloc = wv * 32 + q * 8;
        async_copy16(zb + (size_t)(rowBase + rloc + srow) * D + (kt + 1) * BK + sslot * 8,
                     (ushort*)sT[cur ^ 1][0] + rloc * BK);
        if (!diag)
          async_copy16(zb + (size_t)(colBase + rloc + srow) * D + (kt + 1) * BK + sslot * 8,
                       (ushort*)sT[cur ^ 1][1] + rloc * BK);
      }
    }

    // ---- compute current buffer ----
    const char* Ab = reinterpret_cast<const char*>(sT[cur][0]);
    const char* Bb = diag ? Ab : reinterpret_cast<const char*>(sT[cur][1]);
#pragma unroll
    for (int kk = 0; kk < 2; ++kk) {
      bf16x8 a[4], b[4];
      const int slot = kk * 4 + laneg;
#pragma unroll
      for (int rf = 0; rf < 4; ++rf) {
        int r = wr * 64 + rf * 16 + colq;
        a[rf] = *reinterpret_cast<const bf16x8*>(Ab + r * 128 + (slot ^ (r & 7)) * 16);
      }
#pragma unroll
      for (int cf = 0; cf < 4; ++cf) {
        int c = wc * 64 + cf * 16 + colq;
        b[cf] = *reinterpret_cast<const bf16x8*>(Bb + c * 128 + (slot ^ (c & 7)) * 16);
      }
#pragma unroll
      for (int rf = 0; rf < 4; ++rf)
#pragma unroll
        for (int cf = 0; cf < 4; ++cf)
          acc[rf][cf] = __builtin_amdgcn_mfma_f32_16x16x32_bf16(a[rf], b[cf], acc[rf][cf], 0, 0, 0);
    }

    if (kt + 1 < KSTEPS) {
      __syncthreads();   // prefetch landed (vmcnt drained) + reads done
      cur ^= 1;
    }
  }

  // ---- dual epilogue ----
  // C layout: col = lane&15, row = (lane>>4)*4 + reg  [m89 verified]
  const int wRowBase = rowBase + wr * 64;
  const int wColBase = colBase + wc * 64;
  const int rmodBase = (wRowBase >= N) ? wRowBase - N : wRowBase;
  const int cmodBase = (wColBase >= N) ? wColBase - N : wColBase;

  float rpos[16], rsinv[16];
  unsigned rlab = 0;
#pragma unroll
  for (int rf = 0; rf < 4; ++rf)
#pragma unroll
    for (int rg = 0; rg < 4; ++rg) {
      int idx = rf * 4 + rg;
      int r = rmodBase + rf * 16 + laneg * 4 + rg;
      rpos[idx] = zpos[r];
      rsinv[idx] = sinv[r];
      rlab |= ((unsigned)labels[r] & 3u) << (idx * 2);
    }

  float s_p[16], c_p[16], sc_p[4], cc_p[4];
#pragma unroll
  for (int i = 0; i < 16; ++i) { s_p[i] = 0.f; c_p[i] = 0.f; }

#pragma unroll
  for (int cf = 0; cf < 4; ++cf) {
    int jc = cmodBase + cf * 16 + colq;
    int lc = labels[jc];
    float pc = zpos[jc];
    float si = sinv[jc];
    int col = wColBase + cf * 16 + colq;
    float scf = 0.f, ccf = 0.f;
#pragma unroll
    for (int rf = 0; rf < 4; ++rf)
#pragma unroll
      for (int rg = 0; rg < 4; ++rg) {
        int idx = rf * 4 + rg;
        int row = wRowBase + rf * 16 + laneg * 4 + rg;
        float sim = acc[rf][cf][rg] * INV_T;
        bool dg = (row == col);
        if (dg) sim = -INF_VAL;
        float e = __expf(sim - 10.f);          // exp(-1e8)==0: diag drops out
        s_p[idx] += e;                          // forward row-sum
        scf += e;                               // transpose col-sum
        int lr = (int)((rlab >> (idx * 2)) & 3u);
        if (lr == lc && !dg) {
          float d = rpos[idx] - pc;
          float w = __expf(-0.5f * d * d);
          c_p[idx] = fmaf(w * si, sim, c_p[idx]);        // fw[r,c] = w*sinv[c]
          ccf = fmaf(w * rsinv[idx], sim, ccf);          // fw[c,r] = w*sinv[r]
        }
      }
    sc_p[cf] = scf;
    cc_p[cf] = ccf;
  }

  // forward: reduce each row over the 16 lanes sharing it
#pragma unroll
  for (int idx = 0; idx < 16; ++idx) {
#pragma unroll
    for (int off = 1; off < 16; off <<= 1) {
      s_p[idx] += __shfl_xor(s_p[idx], off);
      c_p[idx] += __shfl_xor(c_p[idx], off);
    }
  }
  if (colq == 0) {
    int m = ct * 2 + wc;
#pragma unroll
    for (int rf = 0; rf < 4; ++rf)
#pragma unroll
      for (int rg = 0; rg < 4; ++rg) {
        int idx = rf * 4 + rg;
        int row = wRowBase + rf * 16 + laneg * 4 + rg;
        s_ws[(size_t)m * twoN + row] = s_p[idx];
        c_ws[(size_t)m * twoN + row] = c_p[idx];
      }
  }

  // transpose: reduce each column over laneg groups (lanes colq,+16,+32,+48)
  if (!diag) {
#pragma unroll
    for (int cf = 0; cf < 4; ++cf) {
      sc_p[cf] += __shfl_xor(sc_p[cf], 16);
      sc_p[cf] += __shfl_xor(sc_p[cf], 32);
      cc_p[cf] += __shfl_xor(cc_p[cf], 16);
      cc_p[cf] += __shfl_xor(cc_p[cf], 32);
    }
    if (laneg == 0) {
      int m = rt * 2 + wr;
#pragma unroll
      for (int cf = 0; cf < 4; ++cf) {
        int rowt = wColBase + cf * 16 + colq;
        s_ws[(size_t)m * twoN + rowt] = sc_p[cf];
        c_ws[(size_t)m * twoN + rowt] = cc_p[cf];
      }
    }
  }
}

// -------------------------------------------------------------------------
// Per-row combine + block partial sum (proven R8 shape, NCHUNK=64 slots).
// 64 blocks x 64 rows. partial[a] = cross_a - wsum_a*(10 + log(sum_m s_ws))
__global__ __launch_bounds__(256) void k_combine(const float* __restrict__ s_ws,
                                                 const float* __restrict__ c_ws,
                                                 const float* __restrict__ sinv,
                                                 const float* __restrict__ tt,
                                                 float* __restrict__ bsum, int N) {
  __shared__ float sS[4][64], sC[4][64];
  int b = blockIdx.x, t = threadIdx.x;
  int r = t & 63, g = t >> 6;
  int twoN = 2 * N;
  int a = b * 64 + r;
  float s = 0.f, c = 0.f;
  for (int k = 0; k < NCHUNK / 4; ++k) {
    int m = g * (NCHUNK / 4) + k;
    s += s_ws[(size_t)m * twoN + a];
    c += c_ws[(size_t)m * twoN + a];
  }
  sS[g][r] = s;
  sC[g][r] = c;
  __syncthreads();
  if (t < 64) {
    float st = sS[0][t] + sS[1][t] + sS[2][t] + sS[3][t];
    float ct = sC[0][t] + sC[1][t] + sC[2][t] + sC[3][t];
    int aa = b * 64 + t;
    int ir = (aa >= N) ? aa - N : aa;
    float lse = 10.f + logf(st);
    float wsum = 2.f * tt[ir] - sinv[ir];
    float p = ct - wsum * lse;
    p = wave_reduce_sum(p);
    if (t == 0) bsum[b] = p;
  }
}

// loss = (-1/N) * sum_b bsum[b]
__global__ __launch_bounds__(64) void k_final(const float* __restrict__ bsum,
                                              float* __restrict__ out, int N) {
  float s = bsum[threadIdx.x];
  s = wave_reduce_sum(s);
  if (threadIdx.x == 0) out[0] = (-1.0f / (float)N) * s;
}

extern "C" void kernel_launch(void* const* d_in, const int* in_sizes, int n_in,
                              void* d_out, int out_size, void* d_ws, size_t ws_size,
                              hipStream_t stream) {
  (void)n_in; (void)out_size; (void)ws_size;
  const float* zi = (const float*)d_in[0];
  const float* zj = (const float*)d_in[1];
  const int* labels = (const int*)d_in[2];
  const float* zpos = (const float*)d_in[3];
  float* out = (float*)d_out;

  const int N = in_sizes[2];       // 2048
  const int twoN = 2 * N;

  // workspace: zb bf16[2N*D] | sinv[N] | tt[N] | s_ws[64*2N] | c_ws[64*2N] | bsum[64]
  char* wsb = (char*)d_ws;
  ushort* zb = (ushort*)wsb;                              // 4 MB
  float* sinv = (float*)(wsb + (size_t)twoN * D * 2);
  float* tt = sinv + N;
  float* s_ws = tt + N;                                   // 1 MB
  float* c_ws = s_ws + (size_t)NCHUNK * twoN;             // 1 MB
  float* bsum = c_ws + (size_t)NCHUNK * twoN;

  k_prep<<<1024 + 2048, 256, 0, stream>>>(zi, zj, zb, labels, zpos, sinv, N);
  k_gemm<<<NBLK + TTBLK, 256, 0, stream>>>(zb, labels, zpos, sinv, tt, s_ws, c_ws, N);
  k_combine<<<twoN / 64, 256, 0, stream>>>(s_ws, c_ws, sinv, tt, bsum, N);
  k_final<<<1, 64, 0, stream>>>(bsum, out, N);
}